// Round 6
// baseline (1810.805 us; speedup 1.0000x reference)
//
#include <hip/hip_runtime.h>

// Problem constants: B=4, C=64 (in & out for deform), H=W=256.
#define BB 4
#define CC 64
#define HH 256
#define WW 256
#define HWHW 65536

typedef __bf16 bf16x8 __attribute__((ext_vector_type(8)));
typedef float f32x16 __attribute__((ext_vector_type(16)));
typedef unsigned int uint2v __attribute__((ext_vector_type(2)));

__device__ __forceinline__ unsigned short f32_to_bf16(float s) {
    unsigned int xi = __builtin_bit_cast(unsigned int, s);
    unsigned int r = (xi + 0x7fffu + ((xi >> 16) & 1u)) >> 16;  // RNE
    return (unsigned short)r;
}

// ---------------------------------------------------------------------------
// Prep:
//   wA[c][k][o18]  fp32, from offset_w[o][c][ky][kx]  (offset conv weights)
//   WB2: bf16 deform weights, TAP-MAJOR K order:
//        [chunk(4)][kslot(18)][n(64)][j(8)], k_local = kslot*8+j,
//        tap = k_local/16, c = chunk*16 + (k_local%16), value = dc_w[n][c][tap]
// ---------------------------------------------------------------------------
__global__ void prep_weights(const float* __restrict__ offset_w,
                             const float* __restrict__ dc_w,
                             float* __restrict__ wA,
                             unsigned short* __restrict__ WB2) {
    int idx = blockIdx.x * 256 + threadIdx.x;
    const int NA = CC * 9 * 18;            // 10368
    const int NB = 4 * 18 * 64 * 8;        // 36864
    if (idx < NA) {
        int c = idx / (9 * 18);
        int k = (idx / 18) % 9;
        int o = idx % 18;
        wA[idx] = offset_w[(o * CC + c) * 9 + k];
    }
    int j = idx - NA;
    if (j >= 0 && j < NB) {
        int chunk = j / 9216;              // 9216 = 18*64*8
        int rem = j - chunk * 9216;
        int kslot = rem >> 9;              // /(64*8)
        int n = (rem >> 3) & 63;
        int jj = rem & 7;
        int k_local = kslot * 8 + jj;      // < 144, tap-major
        int tap = k_local >> 4;
        int c_local = k_local & 15;
        int c = chunk * 16 + c_local;
        WB2[j] = f32_to_bf16(dc_w[(n * CC + c) * 9 + tap]);
    }
}

// ---------------------------------------------------------------------------
// Offset conv v4: 3x3, pad 1, 64 -> 18 ch. Direct-gather body (proven v1
// structure) + explicit double-buffered channel pipeline (sA/sB: 9 loads for
// channel c+1 issued before the 162-FMA block of channel c) so every load
// has a full FMA block of latency cover. Parallelism: block = 128 px x 2
// channel-halves (32 ch/thread), grid = 2*B*H = 2048 blocks -> 8 blocks/CU.
// launch_bounds(256,4): VGPR cap 128 -> no spill, deep load batching.
// fp32-exact within each half; single fp32 add at the join (as v3, passed).
// ---------------------------------------------------------------------------
__global__ __launch_bounds__(256, 4) void offset_conv(
    const float* __restrict__ blur, const float* __restrict__ wA,
    const float* __restrict__ ob, float* __restrict__ offout) {
    __shared__ float red[18 * 128];        // 9216 B
    const int t = threadIdx.x;
    const int xl = t & 127;                // pixel within half-row
    const int h = t >> 7;                  // channel half (wave-uniform)
    const int blk = blockIdx.x;
    const int xh = blk & 1;
    const int y = (blk >> 1) & (HH - 1);
    const int b = blk >> 9;
    const int x = xh * 128 + xl;

    int rb[3], cx[3];
    float m[9];
#pragma unroll
    for (int dy = 0; dy < 3; ++dy) {
        int yy = y + dy - 1;
        rb[dy] = min(max(yy, 0), HH - 1) * WW;
        bool vy = (yy >= 0) && (yy < HH);
#pragma unroll
        for (int dx = 0; dx < 3; ++dx) {
            int xx = x + dx - 1;
            bool v = vy && (xx >= 0) && (xx < WW);
            m[dy * 3 + dx] = v ? 1.0f : 0.0f;
        }
    }
#pragma unroll
    for (int dx = 0; dx < 3; ++dx) cx[dx] = min(max(x + dx - 1, 0), WW - 1);

    float acc[18];
#pragma unroll
    for (int o = 0; o < 18; ++o) acc[o] = (h == 0) ? ob[o] : 0.0f;

    const float* img = blur + (size_t)b * CC * HWHW + (size_t)(h * 32) * HWHW;

    float sA[9], sB[9];
    // ---- preload channel 0 ----
    {
        const float* pl = img;
#pragma unroll
        for (int r = 0; r < 3; ++r)
#pragma unroll
            for (int dx = 0; dx < 3; ++dx)
                sA[r * 3 + dx] = pl[rb[r] + cx[dx]] * m[r * 3 + dx];
    }

#pragma unroll 1
    for (int c = 0; c < 32; c += 2) {
        // prefetch channel c+1 into sB (covered by FMA(sA))
        {
            const float* pl = img + (size_t)(c + 1) * HWHW;
#pragma unroll
            for (int r = 0; r < 3; ++r)
#pragma unroll
                for (int dx = 0; dx < 3; ++dx)
                    sB[r * 3 + dx] = pl[rb[r] + cx[dx]] * m[r * 3 + dx];
        }
        // FMA block for channel c (weights uniform -> s_load)
        {
            const float* wp = wA + (size_t)(h * 32 + c) * 162;
#pragma unroll
            for (int k = 0; k < 9; ++k) {
                const float sv = sA[k];
#pragma unroll
                for (int o = 0; o < 18; ++o)
                    acc[o] = fmaf(sv, wp[k * 18 + o], acc[o]);
            }
        }
        // prefetch channel c+2 into sA (covered by FMA(sB))
        if (c + 2 < 32) {
            const float* pl = img + (size_t)(c + 2) * HWHW;
#pragma unroll
            for (int r = 0; r < 3; ++r)
#pragma unroll
                for (int dx = 0; dx < 3; ++dx)
                    sA[r * 3 + dx] = pl[rb[r] + cx[dx]] * m[r * 3 + dx];
        }
        // FMA block for channel c+1
        {
            const float* wp = wA + (size_t)(h * 32 + c + 1) * 162;
#pragma unroll
            for (int k = 0; k < 9; ++k) {
                const float sv = sB[k];
#pragma unroll
                for (int o = 0; o < 18; ++o)
                    acc[o] = fmaf(sv, wp[k * 18 + o], acc[o]);
            }
        }
    }

    // ---- cross-half reduction via LDS ----
    if (h == 1) {
#pragma unroll
        for (int o = 0; o < 18; ++o) red[o * 128 + xl] = acc[o];
    }
    __syncthreads();
    if (h == 0) {
        float* op = offout + ((size_t)b * 18) * HWHW + y * WW + x;
#pragma unroll
        for (int o = 0; o < 18; ++o)
            op[(size_t)o * HWHW] = acc[o] + red[o * 128 + xl];
    }
}

// ---------------------------------------------------------------------------
// NCHW -> NHWC transpose of content into workspace: ct[(b*HW + p)*64 + c].
// ---------------------------------------------------------------------------
__global__ __launch_bounds__(256) void nchw_to_nhwc(
    const float* __restrict__ in, float* __restrict__ ct) {
    __shared__ float tile[64][65];
    const int t = threadIdx.x;
    const int blk = blockIdx.x;
    const int xseg = blk & 3;
    const int y = (blk >> 2) & (HH - 1);
    const int b = blk >> 10;
    const int px = t & 63;
    const int q = t >> 6;

    const float* src = in + (size_t)b * CC * HWHW + y * WW + xseg * 64;
#pragma unroll
    for (int i = 0; i < 16; ++i) {
        const int c = i * 4 + q;
        tile[c][px] = src[(size_t)c * HWHW + px];
    }
    __syncthreads();
    float* dst = ct + ((size_t)b * HWHW + y * WW + xseg * 64) * 64;
#pragma unroll
    for (int i = 0; i < 16; ++i) {
        const int p = i * 4 + q;
        dst[(size_t)p * 64 + px] = tile[px][p];   // lane = channel, coalesced
    }
}

// ---------------------------------------------------------------------------
// Deformable conv as implicit GEMM on MFMA — NHWC coalesced producer.
// (Proven round-3 version: 211 us, 64 VGPR, no setprio, launch_bounds(256,4).)
// LDS: samp 18432 + stateW 9216 + stateV 9216 = 36864 -> 4 blocks/CU.
// ---------------------------------------------------------------------------
__global__ __launch_bounds__(256, 4) void deform_mfma_nhwc(
    const float* __restrict__ ct, const float* __restrict__ offs,
    const unsigned short* __restrict__ WB2, const float* __restrict__ bias,
    float* __restrict__ out) {
    __shared__ __align__(16) char ldsbuf[36864];
    unsigned int* sampU = (unsigned int*)ldsbuf;            // [18][64][4] u32
    float4* stateW = (float4*)(ldsbuf + 18432);             // [576]
    uint4* stateV = (uint4*)(ldsbuf + 27648);               // [576]
    float* ldsOut = (float*)ldsbuf;                         // [64][65] epilogue alias

    const int t = threadIdx.x;
    const int blk = blockIdx.x;
    const int xseg = blk & 3;
    const int y = (blk >> 2) & (HH - 1);
    const int b = blk >> 10;

    // ---- phase 0: bilinear state for 64 px x 9 taps ----
    {
        const float* offbase = offs + (size_t)b * 18 * HWHW + y * WW + xseg * 64;
        for (int i = t; i < 576; i += 256) {
            const int p = i & 63;
            const int tap = i >> 6;
            const int ky = tap / 3, kx = tap - ky * 3;
            const float offy = offbase[(size_t)(2 * tap) * HWHW + p];
            const float offx = offbase[(size_t)(2 * tap + 1) * HWHW + p];
            const float py = (float)(y + ky - 1) + offy;
            const float pxf = (float)(xseg * 64 + p + kx - 1) + offx;
            const float y0f = floorf(py), x0f = floorf(pxf);
            const float wy = py - y0f, wx = pxf - x0f;
            const int y0 = (int)y0f, x0 = (int)x0f;

            float a00 = (1.0f - wy) * (1.0f - wx);
            float a01 = (1.0f - wy) * wx;
            float a10 = wy * (1.0f - wx);
            float a11 = wy * wx;
            const bool vy0 = (y0 >= 0) && (y0 < HH);
            const bool vy1 = (y0 + 1 >= 0) && (y0 + 1 < HH);
            const bool vx0 = (x0 >= 0) && (x0 < WW);
            const bool vx1 = (x0 + 1 >= 0) && (x0 + 1 < WW);
            float4 w;
            w.x = (vy0 && vx0) ? a00 : 0.0f;
            w.y = (vy0 && vx1) ? a01 : 0.0f;
            w.z = (vy1 && vx0) ? a10 : 0.0f;
            w.w = (vy1 && vx1) ? a11 : 0.0f;

            const int y0c = min(max(y0, 0), HH - 1);
            const int y1c = min(max(y0 + 1, 0), HH - 1);
            const int x0c = min(max(x0, 0), WW - 1);
            const int x1c = min(max(x0 + 1, 0), WW - 1);
            const unsigned int v00 = (unsigned int)(y0c * WW + x0c) << 8;  // *256B
            const unsigned int dxb = (unsigned int)(x1c - x0c) << 8;       // 0|256
            const unsigned int dyb = (unsigned int)(y1c - y0c) << 16;      // 0|65536

            stateW[i] = w;
            uint4 v;
            v.x = v00;
            v.y = v00 + dxb;
            v.z = v00 + dyb;
            v.w = v00 + dyb + dxb;
            stateV[i] = v;
        }
    }
    __syncthreads();

    const char* ctb = (const char*)(ct + (size_t)b * HWHW * 64);

    f32x16 acc = {0, 0, 0, 0, 0, 0, 0, 0, 0, 0, 0, 0, 0, 0, 0, 0};

    const int lane = t & 63;
    const int wv = t >> 6;
    const int l3 = lane >> 3;            // pair sub-index 0..7
    const int clb = (lane & 7) * 8;      // lane's 2-channel byte offset
    const int hlf = lane >> 5;
    const int l31 = lane & 31;
    const int px_i = ((wv >> 1) * 32) + l31;   // A-frag pixel row
    const int n_i = ((wv & 1) * 32) + l31;     // B-frag out-channel col

    for (int chunk = 0; chunk < 4; ++chunk) {
        // ---- producer: 144 pairs/wave, 8 pairs/iter, 2 channels/lane ----
        {
            const int cb = chunk * 64 + clb;   // chunk's 16-channel byte window
#pragma unroll 6
            for (int it = 0; it < 18; ++it) {
                const int j = wv * 144 + it * 8 + l3;
                const float4 w = stateW[j];
                const uint4 vo = stateV[j];
                const float2 v00 = *(const float2*)(ctb + (vo.x + cb));
                const float2 v01 = *(const float2*)(ctb + (vo.y + cb));
                const float2 v10 = *(const float2*)(ctb + (vo.z + cb));
                const float2 v11 = *(const float2*)(ctb + (vo.w + cb));
                const float s0 = w.x * v00.x + w.y * v01.x + w.z * v10.x + w.w * v11.x;
                const float s1 = w.x * v00.y + w.y * v01.y + w.z * v10.y + w.w * v11.y;
                unsigned int pk;
                asm("v_cvt_pk_bf16_f32 %0, %1, %2" : "=v"(pk) : "v"(s0), "v"(s1));
                const int tap = j >> 6;
                const int px = j & 63;
                sampU[(tap * 2 + ((lane >> 2) & 1)) * 256 + px * 4 + (lane & 3)] = pk;
            }
        }
        __syncthreads();

        // ---- MFMA: 9 x K16; B-frags direct from global (L2-hot 36KB) ----
        {
            const bf16x8* sampV = (const bf16x8*)sampU;
            const bf16x8* wV = (const bf16x8*)(WB2 + (size_t)chunk * 9216);
#pragma unroll
            for (int ks = 0; ks < 9; ++ks) {
                bf16x8 fa = sampV[(ks * 2 + hlf) * 64 + px_i];
                bf16x8 fb = wV[(ks * 2 + hlf) * 64 + n_i];
                acc = __builtin_amdgcn_mfma_f32_32x32x16_bf16(fa, fb, acc, 0, 0, 0);
            }
        }
        __syncthreads();
    }

    // ---- epilogue: transpose via LDS (stride 65, bank-clean), coalesced out ----
    {
        const int n_l = (wv & 1) * 32 + l31;
        const int px_base = (wv >> 1) * 32 + 4 * hlf;
#pragma unroll
        for (int r = 0; r < 16; ++r) {
            const int row = px_base + (r & 3) + 8 * (r >> 2);
            ldsOut[n_l * 65 + row] = acc[r];
        }
    }
    __syncthreads();
    {
        float* base = out + (size_t)b * CC * HWHW + y * WW + xseg * 64;
        for (int i = t; i < 4096; i += 256) {
            const int n = i >> 6;
            const int p = i & 63;
            base[(size_t)n * HWHW + p] = ldsOut[n * 65 + p] + bias[n];
        }
    }
}

// ---------------------------------------------------------------------------
// Fallback deform (only if workspace too small): global scattered gather,
// tap-major K (matches WB2).
// ---------------------------------------------------------------------------
__global__ __launch_bounds__(256) void deform_mfma_gather(
    const float* __restrict__ content, const float* __restrict__ offs,
    const unsigned short* __restrict__ WB2, const float* __restrict__ bias,
    float* __restrict__ out) {
    __shared__ __align__(16) char ldsbuf[29952];
    unsigned int* sampU = (unsigned int*)ldsbuf;            // [18][64][4]
    float4* stateW = (float4*)(ldsbuf + 18432);             // [576]
    unsigned int* stateI = (unsigned int*)(ldsbuf + 27648); // [576]
    float* ldsOut = (float*)ldsbuf;

    const int t = threadIdx.x;
    const int px = t & 63;
    const int cg = t >> 6;
    const int blk = blockIdx.x;
    const int xseg = blk & 3;
    const int y = (blk >> 2) & (HH - 1);
    const int b = blk >> 10;

    {
        const float* offbase = offs + (size_t)b * 18 * HWHW + y * WW + xseg * 64;
        for (int i = t; i < 576; i += 256) {
            const int p = i & 63;
            const int tap = i >> 6;
            const int ky = tap / 3, kx = tap - ky * 3;
            const float offy = offbase[(size_t)(2 * tap) * HWHW + p];
            const float offx = offbase[(size_t)(2 * tap + 1) * HWHW + p];
            const float py = (float)(y + ky - 1) + offy;
            const float pxf = (float)(xseg * 64 + p + kx - 1) + offx;
            const float y0f = floorf(py), x0f = floorf(pxf);
            const float wy = py - y0f, wx = pxf - x0f;
            const int y0 = (int)y0f, x0 = (int)x0f;
            float a00 = (1.0f - wy) * (1.0f - wx);
            float a01 = (1.0f - wy) * wx;
            float a10 = wy * (1.0f - wx);
            float a11 = wy * wx;
            const bool vy0 = (y0 >= 0) && (y0 < HH);
            const bool vy1 = (y0 + 1 >= 0) && (y0 + 1 < HH);
            const bool vx0 = (x0 >= 0) && (x0 < WW);
            const bool vx1 = (x0 + 1 >= 0) && (x0 + 1 < WW);
            float4 w;
            w.x = (vy0 && vx0) ? a00 : 0.0f;
            w.y = (vy0 && vx1) ? a01 : 0.0f;
            w.z = (vy1 && vx0) ? a10 : 0.0f;
            w.w = (vy1 && vx1) ? a11 : 0.0f;
            const int y0c = min(max(y0, 0), HH - 1);
            const int y1c = min(max(y0 + 1, 0), HH - 1);
            const int x0c = min(max(x0, 0), WW - 1);
            const int x1c = min(max(x0 + 1, 0), WW - 1);
            stateW[i] = w;
            stateI[i] = (unsigned int)(y0c * WW + x0c) |
                        ((unsigned int)(x1c - x0c) << 16) |
                        ((unsigned int)(y1c - y0c) << 17);
        }
    }
    __syncthreads();

    const float* img = content + (size_t)b * CC * HWHW;
    f32x16 acc = {0, 0, 0, 0, 0, 0, 0, 0, 0, 0, 0, 0, 0, 0, 0, 0};
    const int lane = t & 63;
    const int hlf = lane >> 5;
    const int l31 = lane & 31;
    const int px_i = ((cg >> 1) * 32) + l31;
    const int n_i = ((cg & 1) * 32) + l31;

    for (int chunk = 0; chunk < 4; ++chunk) {
        const int cbase = (chunk * 16 + cg * 4) << 16;
#pragma unroll 3
        for (int tap = 0; tap < 9; ++tap) {
            const float4 w = stateW[tap * 64 + px];
            const unsigned int ii = stateI[tap * 64 + px];
            const int i0 = (int)(ii & 0xFFFFu);
            const int dx = (int)((ii >> 16) & 1u);
            const int dyw = ((int)((ii >> 17) & 1u)) << 8;
            unsigned int pk0 = 0, pk1 = 0;
#pragma unroll
            for (int i = 0; i < 4; ++i) {
                const int cb = cbase + (i << 16);
                const float v00 = img[cb + i0];
                const float v01 = img[cb + i0 + dx];
                const float v10 = img[cb + i0 + dyw];
                const float v11 = img[cb + i0 + dyw + dx];
                const float s = w.x * v00 + w.y * v01 + w.z * v10 + w.w * v11;
                const unsigned int u = f32_to_bf16(s);
                if (i == 0) pk0 = u;
                else if (i == 1) pk0 |= u << 16;
                else if (i == 2) pk1 = u;
                else pk1 |= u << 16;
            }
            uint2v v2 = {pk0, pk1};
            *(uint2v*)&sampU[(tap * 2 + (cg >> 1)) * 256 + px * 4 + (cg & 1) * 2] = v2;
        }
        __syncthreads();
        {
            const bf16x8* sampV = (const bf16x8*)sampU;
            const bf16x8* wV = (const bf16x8*)(WB2 + (size_t)chunk * 9216);
#pragma unroll
            for (int ks = 0; ks < 9; ++ks) {
                bf16x8 fa = sampV[(ks * 2 + hlf) * 64 + px_i];
                bf16x8 fb = wV[(ks * 2 + hlf) * 64 + n_i];
                acc = __builtin_amdgcn_mfma_f32_32x32x16_bf16(fa, fb, acc, 0, 0, 0);
            }
        }
        __syncthreads();
    }

    {
        const int n_l = (cg & 1) * 32 + l31;
        const int px_base = (cg >> 1) * 32 + 4 * hlf;
#pragma unroll
        for (int r = 0; r < 16; ++r) {
            const int row = px_base + (r & 3) + 8 * (r >> 2);
            ldsOut[n_l * 65 + row] = acc[r];
        }
    }
    __syncthreads();
    {
        float* base = out + (size_t)b * CC * HWHW + y * WW + xseg * 64;
        for (int i = t; i < 4096; i += 256) {
            const int n = i >> 6;
            const int p = i & 63;
            base[(size_t)n * HWHW + p] = ldsOut[n * 65 + p] + bias[n];
        }
    }
}

// ---------------------------------------------------------------------------
extern "C" void kernel_launch(void* const* d_in, const int* in_sizes, int n_in,
                              void* d_out, int out_size, void* d_ws, size_t ws_size,
                              hipStream_t stream) {
    const float* content  = (const float*)d_in[0];
    const float* blur     = (const float*)d_in[1];
    const float* offset_w = (const float*)d_in[2];
    const float* offset_b = (const float*)d_in[3];
    const float* dc_w     = (const float*)d_in[4];
    const float* dc_b     = (const float*)d_in[5];

    float* out0    = (float*)d_out;                                // (4,64,256,256)
    float* off_out = out0 + (size_t)BB * CC * HWHW;                // (4,18,256,256)

    float* wA = (float*)d_ws;                                   // 10368 floats
    unsigned short* WB2 = (unsigned short*)(wA + CC * 9 * 18);  // 36864 bf16

    const size_t CT_OFF = 131072;                               // bytes
    const size_t WS_NEED = CT_OFF + (size_t)BB * HWHW * CC * 4; // + 64 MiB

    const int NPREP = CC * 9 * 18 + 4 * 18 * 64 * 8;        // 47232
    prep_weights<<<(NPREP + 255) / 256, 256, 0, stream>>>(offset_w, dc_w, wA, WB2);
    offset_conv<<<BB * HH * 2, 256, 0, stream>>>(blur, wA, offset_b, off_out);

    if (ws_size >= WS_NEED) {
        float* ct = (float*)((char*)d_ws + CT_OFF);
        nchw_to_nhwc<<<BB * HH * 4, 256, 0, stream>>>(content, ct);
        deform_mfma_nhwc<<<BB * HH * 4, 256, 0, stream>>>(ct, off_out, WB2, dc_b, out0);
    } else {
        deform_mfma_gather<<<BB * HH * 4, 256, 0, stream>>>(content, off_out, WB2, dc_b, out0);
    }
}

// Round 8
// 435.195 us; speedup vs baseline: 4.1609x; 4.1609x over previous
//
#include <hip/hip_runtime.h>

// Problem constants: B=4, C=64 (in & out for deform), H=W=256.
#define BB 4
#define CC 64
#define HH 256
#define WW 256
#define HWHW 65536

typedef __bf16 bf16x8 __attribute__((ext_vector_type(8)));
typedef float f32x16 __attribute__((ext_vector_type(16)));
typedef unsigned int uint2v __attribute__((ext_vector_type(2)));

__device__ __forceinline__ unsigned short f32_to_bf16(float s) {
    unsigned int xi = __builtin_bit_cast(unsigned int, s);
    unsigned int r = (xi + 0x7fffu + ((xi >> 16) & 1u)) >> 16;  // RNE
    return (unsigned short)r;
}

// ---------------------------------------------------------------------------
// Prep:
//   wA[c][k][o18]  fp32, from offset_w[o][c][ky][kx]  (offset conv weights)
//   WB2: bf16 deform weights, TAP-MAJOR K order:
//        [chunk(4)][kslot(18)][n(64)][j(8)], k_local = kslot*8+j,
//        tap = k_local/16, c = chunk*16 + (k_local%16), value = dc_w[n][c][tap]
// ---------------------------------------------------------------------------
__global__ void prep_weights(const float* __restrict__ offset_w,
                             const float* __restrict__ dc_w,
                             float* __restrict__ wA,
                             unsigned short* __restrict__ WB2) {
    int idx = blockIdx.x * 256 + threadIdx.x;
    const int NA = CC * 9 * 18;            // 10368
    const int NB = 4 * 18 * 64 * 8;        // 36864
    if (idx < NA) {
        int c = idx / (9 * 18);
        int k = (idx / 18) % 9;
        int o = idx % 18;
        wA[idx] = offset_w[(o * CC + c) * 9 + k];
    }
    int j = idx - NA;
    if (j >= 0 && j < NB) {
        int chunk = j / 9216;              // 9216 = 18*64*8
        int rem = j - chunk * 9216;
        int kslot = rem >> 9;              // /(64*8)
        int n = (rem >> 3) & 63;
        int jj = rem & 7;
        int k_local = kslot * 8 + jj;      // < 144, tap-major
        int tap = k_local >> 4;
        int c_local = k_local & 15;
        int c = chunk * 16 + c_local;
        WB2[j] = f32_to_bf16(dc_w[(n * CC + c) * 9 + tap]);
    }
}

// ---------------------------------------------------------------------------
// Offset conv (proven v1, fp32-exact): 3x3, pad 1, 64 -> 18 channels.
// DO NOT restructure: v2 (LDS staging), v3 (512thr), v4 (dbuf pipeline) all
// regressed 2-7x via compiler allocation pathologies (VGPR 32/64 + scratch
// spill). This body measured ~190 us.
// ---------------------------------------------------------------------------
__global__ __launch_bounds__(256) void offset_conv(
    const float* __restrict__ blur, const float* __restrict__ wA,
    const float* __restrict__ ob, float* __restrict__ offout) {
    const int x = threadIdx.x;
    const int y = blockIdx.x & (HH - 1);
    const int b = blockIdx.x >> 8;

    int rb[3], cx[3];
    float m[9];
#pragma unroll
    for (int dy = 0; dy < 3; ++dy) {
        int yy = y + dy - 1;
        rb[dy] = min(max(yy, 0), HH - 1) * WW;
        bool vy = (yy >= 0) && (yy < HH);
#pragma unroll
        for (int dx = 0; dx < 3; ++dx) {
            int xx = x + dx - 1;
            bool v = vy && (xx >= 0) && (xx < WW);
            m[dy * 3 + dx] = v ? 1.0f : 0.0f;
        }
    }
#pragma unroll
    for (int dx = 0; dx < 3; ++dx) cx[dx] = min(max(x + dx - 1, 0), WW - 1);

    float acc[18];
#pragma unroll
    for (int o = 0; o < 18; ++o) acc[o] = ob[o];

    const float* img = blur + (size_t)b * CC * HWHW;
    for (int c = 0; c < CC; ++c) {
        const float* pl = img + c * HWHW;
        float s[9];
#pragma unroll
        for (int dy = 0; dy < 3; ++dy)
#pragma unroll
            for (int dx = 0; dx < 3; ++dx)
                s[dy * 3 + dx] = pl[rb[dy] + cx[dx]] * m[dy * 3 + dx];

        const float* wp = wA + c * 9 * 18;
#pragma unroll
        for (int k = 0; k < 9; ++k) {
            float sv = s[k];
#pragma unroll
            for (int o = 0; o < 18; ++o)
                acc[o] = fmaf(sv, wp[k * 18 + o], acc[o]);
        }
    }

    float* op = offout + ((size_t)b * 18) * HWHW + y * WW + x;
#pragma unroll
    for (int o = 0; o < 18; ++o) op[(size_t)o * HWHW] = acc[o];
}

// ---------------------------------------------------------------------------
// NCHW -> NHWC transpose of content into workspace: ct[(b*HW + p)*64 + c].
// ---------------------------------------------------------------------------
__global__ __launch_bounds__(256) void nchw_to_nhwc(
    const float* __restrict__ in, float* __restrict__ ct) {
    __shared__ float tile[64][65];
    const int t = threadIdx.x;
    const int blk = blockIdx.x;
    const int xseg = blk & 3;
    const int y = (blk >> 2) & (HH - 1);
    const int b = blk >> 10;
    const int px = t & 63;
    const int q = t >> 6;

    const float* src = in + (size_t)b * CC * HWHW + y * WW + xseg * 64;
#pragma unroll
    for (int i = 0; i < 16; ++i) {
        const int c = i * 4 + q;
        tile[c][px] = src[(size_t)c * HWHW + px];
    }
    __syncthreads();
    float* dst = ct + ((size_t)b * HWHW + y * WW + xseg * 64) * 64;
#pragma unroll
    for (int i = 0; i < 16; ++i) {
        const int p = i * 4 + q;
        dst[(size_t)p * 64 + px] = tile[px][p];   // lane = channel, coalesced
    }
}

// ---------------------------------------------------------------------------
// Deformable conv as implicit GEMM on MFMA — NHWC coalesced producer.
// (Proven round-3 version: 211 us, 64 VGPR, launch_bounds(256,4).)
// XCD-bijective blockIdx swizzle (4096 blocks, 8 XCDs, cpx=512) so each XCD
// processes a contiguous (y,xseg) run -> per-XCD L2 reuse of neighboring ct
// rows. Pure index relabeling, bit-identical math.
// LDS: samp 18432 + stateW 9216 + stateV 9216 = 36864 -> 4 blocks/CU.
// ---------------------------------------------------------------------------
__global__ __launch_bounds__(256, 4) void deform_mfma_nhwc(
    const float* __restrict__ ct, const float* __restrict__ offs,
    const unsigned short* __restrict__ WB2, const float* __restrict__ bias,
    float* __restrict__ out) {
    __shared__ __align__(16) char ldsbuf[36864];
    unsigned int* sampU = (unsigned int*)ldsbuf;            // [18][64][4] u32
    float4* stateW = (float4*)(ldsbuf + 18432);             // [576]
    uint4* stateV = (uint4*)(ldsbuf + 27648);               // [576]
    float* ldsOut = (float*)ldsbuf;                         // [64][65] epilogue alias

    const int t = threadIdx.x;
    const int raw = blockIdx.x;
    const int blk = (raw & 7) * 512 + (raw >> 3);   // XCD-bijective swizzle
    const int xseg = blk & 3;
    const int y = (blk >> 2) & (HH - 1);
    const int b = blk >> 10;

    // ---- phase 0: bilinear state for 64 px x 9 taps ----
    {
        const float* offbase = offs + (size_t)b * 18 * HWHW + y * WW + xseg * 64;
        for (int i = t; i < 576; i += 256) {
            const int p = i & 63;
            const int tap = i >> 6;
            const int ky = tap / 3, kx = tap - ky * 3;
            const float offy = offbase[(size_t)(2 * tap) * HWHW + p];
            const float offx = offbase[(size_t)(2 * tap + 1) * HWHW + p];
            const float py = (float)(y + ky - 1) + offy;
            const float pxf = (float)(xseg * 64 + p + kx - 1) + offx;
            const float y0f = floorf(py), x0f = floorf(pxf);
            const float wy = py - y0f, wx = pxf - x0f;
            const int y0 = (int)y0f, x0 = (int)x0f;

            float a00 = (1.0f - wy) * (1.0f - wx);
            float a01 = (1.0f - wy) * wx;
            float a10 = wy * (1.0f - wx);
            float a11 = wy * wx;
            const bool vy0 = (y0 >= 0) && (y0 < HH);
            const bool vy1 = (y0 + 1 >= 0) && (y0 + 1 < HH);
            const bool vx0 = (x0 >= 0) && (x0 < WW);
            const bool vx1 = (x0 + 1 >= 0) && (x0 + 1 < WW);
            float4 w;
            w.x = (vy0 && vx0) ? a00 : 0.0f;
            w.y = (vy0 && vx1) ? a01 : 0.0f;
            w.z = (vy1 && vx0) ? a10 : 0.0f;
            w.w = (vy1 && vx1) ? a11 : 0.0f;

            const int y0c = min(max(y0, 0), HH - 1);
            const int y1c = min(max(y0 + 1, 0), HH - 1);
            const int x0c = min(max(x0, 0), WW - 1);
            const int x1c = min(max(x0 + 1, 0), WW - 1);
            const unsigned int v00 = (unsigned int)(y0c * WW + x0c) << 8;  // *256B
            const unsigned int dxb = (unsigned int)(x1c - x0c) << 8;       // 0|256
            const unsigned int dyb = (unsigned int)(y1c - y0c) << 16;      // 0|65536

            stateW[i] = w;
            uint4 v;
            v.x = v00;
            v.y = v00 + dxb;
            v.z = v00 + dyb;
            v.w = v00 + dyb + dxb;
            stateV[i] = v;
        }
    }
    __syncthreads();

    const char* ctb = (const char*)(ct + (size_t)b * HWHW * 64);

    f32x16 acc = {0, 0, 0, 0, 0, 0, 0, 0, 0, 0, 0, 0, 0, 0, 0, 0};

    const int lane = t & 63;
    const int wv = t >> 6;
    const int l3 = lane >> 3;            // pair sub-index 0..7
    const int clb = (lane & 7) * 8;      // lane's 2-channel byte offset
    const int hlf = lane >> 5;
    const int l31 = lane & 31;
    const int px_i = ((wv >> 1) * 32) + l31;   // A-frag pixel row
    const int n_i = ((wv & 1) * 32) + l31;     // B-frag out-channel col

    for (int chunk = 0; chunk < 4; ++chunk) {
        // ---- producer: 144 pairs/wave, 8 pairs/iter, 2 channels/lane ----
        {
            const int cb = chunk * 64 + clb;   // chunk's 16-channel byte window
#pragma unroll 6
            for (int it = 0; it < 18; ++it) {
                const int j = wv * 144 + it * 8 + l3;
                const float4 w = stateW[j];
                const uint4 vo = stateV[j];
                const float2 v00 = *(const float2*)(ctb + (vo.x + cb));
                const float2 v01 = *(const float2*)(ctb + (vo.y + cb));
                const float2 v10 = *(const float2*)(ctb + (vo.z + cb));
                const float2 v11 = *(const float2*)(ctb + (vo.w + cb));
                const float s0 = w.x * v00.x + w.y * v01.x + w.z * v10.x + w.w * v11.x;
                const float s1 = w.x * v00.y + w.y * v01.y + w.z * v10.y + w.w * v11.y;
                unsigned int pk;
                asm("v_cvt_pk_bf16_f32 %0, %1, %2" : "=v"(pk) : "v"(s0), "v"(s1));
                const int tap = j >> 6;
                const int px = j & 63;
                sampU[(tap * 2 + ((lane >> 2) & 1)) * 256 + px * 4 + (lane & 3)] = pk;
            }
        }
        __syncthreads();

        // ---- MFMA: 9 x K16; B-frags direct from global (L2-hot 36KB) ----
        {
            const bf16x8* sampV = (const bf16x8*)sampU;
            const bf16x8* wV = (const bf16x8*)(WB2 + (size_t)chunk * 9216);
#pragma unroll
            for (int ks = 0; ks < 9; ++ks) {
                bf16x8 fa = sampV[(ks * 2 + hlf) * 64 + px_i];
                bf16x8 fb = wV[(ks * 2 + hlf) * 64 + n_i];
                acc = __builtin_amdgcn_mfma_f32_32x32x16_bf16(fa, fb, acc, 0, 0, 0);
            }
        }
        __syncthreads();
    }

    // ---- epilogue: transpose via LDS (stride 65, bank-clean), coalesced out ----
    {
        const int n_l = (wv & 1) * 32 + l31;
        const int px_base = (wv >> 1) * 32 + 4 * hlf;
#pragma unroll
        for (int r = 0; r < 16; ++r) {
            const int row = px_base + (r & 3) + 8 * (r >> 2);
            ldsOut[n_l * 65 + row] = acc[r];
        }
    }
    __syncthreads();
    {
        float* base = out + (size_t)b * CC * HWHW + y * WW + xseg * 64;
        for (int i = t; i < 4096; i += 256) {
            const int n = i >> 6;
            const int p = i & 63;
            base[(size_t)n * HWHW + p] = ldsOut[n * 65 + p] + bias[n];
        }
    }
}

// ---------------------------------------------------------------------------
// Fallback deform (only if workspace too small): global scattered gather,
// tap-major K (matches WB2).
// ---------------------------------------------------------------------------
__global__ __launch_bounds__(256) void deform_mfma_gather(
    const float* __restrict__ content, const float* __restrict__ offs,
    const unsigned short* __restrict__ WB2, const float* __restrict__ bias,
    float* __restrict__ out) {
    __shared__ __align__(16) char ldsbuf[29952];
    unsigned int* sampU = (unsigned int*)ldsbuf;            // [18][64][4]
    float4* stateW = (float4*)(ldsbuf + 18432);             // [576]
    unsigned int* stateI = (unsigned int*)(ldsbuf + 27648); // [576]
    float* ldsOut = (float*)ldsbuf;

    const int t = threadIdx.x;
    const int px = t & 63;
    const int cg = t >> 6;
    const int blk = blockIdx.x;
    const int xseg = blk & 3;
    const int y = (blk >> 2) & (HH - 1);
    const int b = blk >> 10;

    {
        const float* offbase = offs + (size_t)b * 18 * HWHW + y * WW + xseg * 64;
        for (int i = t; i < 576; i += 256) {
            const int p = i & 63;
            const int tap = i >> 6;
            const int ky = tap / 3, kx = tap - ky * 3;
            const float offy = offbase[(size_t)(2 * tap) * HWHW + p];
            const float offx = offbase[(size_t)(2 * tap + 1) * HWHW + p];
            const float py = (float)(y + ky - 1) + offy;
            const float pxf = (float)(xseg * 64 + p + kx - 1) + offx;
            const float y0f = floorf(py), x0f = floorf(pxf);
            const float wy = py - y0f, wx = pxf - x0f;
            const int y0 = (int)y0f, x0 = (int)x0f;
            float a00 = (1.0f - wy) * (1.0f - wx);
            float a01 = (1.0f - wy) * wx;
            float a10 = wy * (1.0f - wx);
            float a11 = wy * wx;
            const bool vy0 = (y0 >= 0) && (y0 < HH);
            const bool vy1 = (y0 + 1 >= 0) && (y0 + 1 < HH);
            const bool vx0 = (x0 >= 0) && (x0 < WW);
            const bool vx1 = (x0 + 1 >= 0) && (x0 + 1 < WW);
            float4 w;
            w.x = (vy0 && vx0) ? a00 : 0.0f;
            w.y = (vy0 && vx1) ? a01 : 0.0f;
            w.z = (vy1 && vx0) ? a10 : 0.0f;
            w.w = (vy1 && vx1) ? a11 : 0.0f;
            const int y0c = min(max(y0, 0), HH - 1);
            const int y1c = min(max(y0 + 1, 0), HH - 1);
            const int x0c = min(max(x0, 0), WW - 1);
            const int x1c = min(max(x0 + 1, 0), WW - 1);
            stateW[i] = w;
            stateI[i] = (unsigned int)(y0c * WW + x0c) |
                        ((unsigned int)(x1c - x0c) << 16) |
                        ((unsigned int)(y1c - y0c) << 17);
        }
    }
    __syncthreads();

    const float* img = content + (size_t)b * CC * HWHW;
    f32x16 acc = {0, 0, 0, 0, 0, 0, 0, 0, 0, 0, 0, 0, 0, 0, 0, 0};
    const int lane = t & 63;
    const int hlf = lane >> 5;
    const int l31 = lane & 31;
    const int px_i = ((cg >> 1) * 32) + l31;
    const int n_i = ((cg & 1) * 32) + l31;

    for (int chunk = 0; chunk < 4; ++chunk) {
        const int cbase = (chunk * 16 + cg * 4) << 16;
#pragma unroll 3
        for (int tap = 0; tap < 9; ++tap) {
            const float4 w = stateW[tap * 64 + px];
            const unsigned int ii = stateI[tap * 64 + px];
            const int i0 = (int)(ii & 0xFFFFu);
            const int dx = (int)((ii >> 16) & 1u);
            const int dyw = ((int)((ii >> 17) & 1u)) << 8;
            unsigned int pk0 = 0, pk1 = 0;
#pragma unroll
            for (int i = 0; i < 4; ++i) {
                const int cb = cbase + (i << 16);
                const float v00 = img[cb + i0];
                const float v01 = img[cb + i0 + dx];
                const float v10 = img[cb + i0 + dyw];
                const float v11 = img[cb + i0 + dyw + dx];
                const float s = w.x * v00 + w.y * v01 + w.z * v10 + w.w * v11;
                const unsigned int u = f32_to_bf16(s);
                if (i == 0) pk0 = u;
                else if (i == 1) pk0 |= u << 16;
                else if (i == 2) pk1 = u;
                else pk1 |= u << 16;
            }
            uint2v v2 = {pk0, pk1};
            *(uint2v*)&sampU[(tap * 2 + (cg >> 1)) * 256 + px * 4 + (cg & 1) * 2] = v2;
        }
        __syncthreads();
        {
            const bf16x8* sampV = (const bf16x8*)sampU;
            const bf16x8* wV = (const bf16x8*)(WB2 + (size_t)chunk * 9216);
#pragma unroll
            for (int ks = 0; ks < 9; ++ks) {
                bf16x8 fa = sampV[(ks * 2 + hlf) * 64 + px_i];
                bf16x8 fb = wV[(ks * 2 + hlf) * 64 + n_i];
                acc = __builtin_amdgcn_mfma_f32_32x32x16_bf16(fa, fb, acc, 0, 0, 0);
            }
        }
        __syncthreads();
    }

    {
        const int n_l = (cg & 1) * 32 + l31;
        const int px_base = (cg >> 1) * 32 + 4 * hlf;
#pragma unroll
        for (int r = 0; r < 16; ++r) {
            const int row = px_base + (r & 3) + 8 * (r >> 2);
            ldsOut[n_l * 65 + row] = acc[r];
        }
    }
    __syncthreads();
    {
        float* base = out + (size_t)b * CC * HWHW + y * WW + xseg * 64;
        for (int i = t; i < 4096; i += 256) {
            const int n = i >> 6;
            const int p = i & 63;
            base[(size_t)n * HWHW + p] = ldsOut[n * 65 + p] + bias[n];
        }
    }
}

// ---------------------------------------------------------------------------
extern "C" void kernel_launch(void* const* d_in, const int* in_sizes, int n_in,
                              void* d_out, int out_size, void* d_ws, size_t ws_size,
                              hipStream_t stream) {
    const float* content  = (const float*)d_in[0];
    const float* blur     = (const float*)d_in[1];
    const float* offset_w = (const float*)d_in[2];
    const float* offset_b = (const float*)d_in[3];
    const float* dc_w     = (const float*)d_in[4];
    const float* dc_b     = (const float*)d_in[5];

    float* out0    = (float*)d_out;                                // (4,64,256,256)
    float* off_out = out0 + (size_t)BB * CC * HWHW;                // (4,18,256,256)

    float* wA = (float*)d_ws;                                   // 10368 floats
    unsigned short* WB2 = (unsigned short*)(wA + CC * 9 * 18);  // 36864 bf16

    const size_t CT_OFF = 131072;                               // bytes
    const size_t WS_NEED = CT_OFF + (size_t)BB * HWHW * CC * 4; // + 64 MiB

    const int NPREP = CC * 9 * 18 + 4 * 18 * 64 * 8;        // 47232
    prep_weights<<<(NPREP + 255) / 256, 256, 0, stream>>>(offset_w, dc_w, wA, WB2);
    offset_conv<<<BB * HH, 256, 0, stream>>>(blur, wA, offset_b, off_out);

    if (ws_size >= WS_NEED) {
        float* ct = (float*)((char*)d_ws + CT_OFF);
        nchw_to_nhwc<<<BB * HH * 4, 256, 0, stream>>>(content, ct);
        deform_mfma_nhwc<<<BB * HH * 4, 256, 0, stream>>>(ct, off_out, WB2, dc_b, out0);
    } else {
        deform_mfma_gather<<<BB * HH * 4, 256, 0, stream>>>(content, off_out, WB2, dc_b, out0);
    }
}